// Round 6
// baseline (173.003 us; speedup 1.0000x reference)
//
#include <hip/hip_runtime.h>

// B=32, T=2048, D=64, K=4, KD=256
// out[b,t,j] = m*ha + (1-m)*(g*h_fwd + (1-g)*ha)
//   d = j % 64, m = M[b,t,d], delta = deltas[b,t,d] in {1,2,3,4} (clamped <= t+1)
//   g = exp(-relu(delta*W[j] + b[j]))
//   h_fwd = h_a[b, t-(int(delta)-1), j]  -> one of rows t, t-1, t-2, t-3
//
// v7: v1 structure at f32x2 granularity -- the last untested lever.
//   Grid-size trend across v1/v2/v3/v6 is monotonic (2048 blk: 49us,
//   4096: 45-47, 8192: 43.5-45.8, 16384: 42-44) and v1 proved VMEM instr
//   rate is NOT the limiter (highest rate, fastest). Doubling wave count
//   (131072 waves, 32768 blocks, 8x8B loads per lane) probes whether
//   request-level parallelism into the saturated ingress queue is the
//   remaining axis. Everything else identical to v1 (nt store, no swizzle).

#define TD_T 2048
#define TD_KD 256
#define TD_D 64

typedef float f32x2 __attribute__((ext_vector_type(2)));

__global__ __launch_bounds__(256) void TemporalDecay_89524298318172_kernel(
    const float* __restrict__ h_a,
    const float* __restrict__ deltas,
    const float* __restrict__ M,
    const float* __restrict__ W,
    const float* __restrict__ bias,
    float* __restrict__ out)
{
    const int gid = blockIdx.x * blockDim.x + threadIdx.x;
    const int q   = gid & 127;       // which float2 within the 256-wide row
    const int row = gid >> 7;        // b*T + t
    const int t   = row & (TD_T - 1);
    const int j0  = q << 1;          // 0..254, even
    const int d0  = j0 & (TD_D - 1); // no wrap inside a float2 (2 | 64)

    const size_t row_off = (size_t)row * TD_KD + j0;

    // All loads issue with no inter-load dependencies.
    const f32x2 ha2 = *(const f32x2*)(h_a    + row_off);
    const f32x2 m2  = *(const f32x2*)(M      + (size_t)row * TD_D + d0);
    const f32x2 dl2 = *(const f32x2*)(deltas + (size_t)row * TD_D + d0);
    const f32x2 w2  = *(const f32x2*)(W    + j0);
    const f32x2 b2  = *(const f32x2*)(bias + j0);

    // Candidate rows t-1, t-2, t-3 (clamped; unselected when t-r < 0 since
    // delta <= t+1 guarantees the selected row index is >= 0).
    const int r1 = (t >= 1) ? t - 1 : 0;
    const int r2 = (t >= 2) ? t - 2 : 0;
    const int r3 = (t >= 3) ? t - 3 : 0;
    const size_t bt_base = (size_t)(row - t) * TD_KD + j0;  // b*T*KD + j0
    const f32x2 c1 = *(const f32x2*)(h_a + bt_base + (size_t)r1 * TD_KD);
    const f32x2 c2 = *(const f32x2*)(h_a + bt_base + (size_t)r2 * TD_KD);
    const f32x2 c3 = *(const f32x2*)(h_a + bt_base + (size_t)r3 * TD_KD);

    f32x2 res;
#pragma unroll
    for (int e = 0; e < 2; ++e) {
        const float delta = dl2[e];
        const float g = __expf(-fmaxf(fmaf(delta, w2[e], b2[e]), 0.0f));
        const int di = (int)delta;  // 1..4
        float hf = ha2[e];
        hf = (di == 2) ? c1[e] : hf;
        hf = (di == 3) ? c2[e] : hf;
        hf = (di == 4) ? c3[e] : hf;
        const float m = m2[e];
        res[e] = m * ha2[e] + (1.0f - m) * (g * hf + (1.0f - g) * ha2[e]);
    }

    __builtin_nontemporal_store(res, (f32x2*)(out + row_off));
}

extern "C" void kernel_launch(void* const* d_in, const int* in_sizes, int n_in,
                              void* d_out, int out_size, void* d_ws, size_t ws_size,
                              hipStream_t stream) {
    const float* h_a    = (const float*)d_in[0];
    const float* deltas = (const float*)d_in[1];
    const float* M      = (const float*)d_in[2];
    const float* W      = (const float*)d_in[3];
    const float* bias   = (const float*)d_in[4];
    float* out          = (float*)d_out;

    // total float2 threads = B*T*KD/2 = 8,388,608
    const int total = in_sizes[0] / 2;
    const int block = 256;
    const int grid = (total + block - 1) / block;  // 32768
    TemporalDecay_89524298318172_kernel<<<grid, block, 0, stream>>>(
        h_a, deltas, M, W, bias, out);
}